// Round 2
// baseline (981.670 us; speedup 1.0000x reference)
//
#include <hip/hip_runtime.h>
#include <cstdint>
#include <cstddef>

// Problem constants: B=32, T=4096, 2H=1024, DFF=512
#define B_SZ 32
#define T_SZ 4096
#define H2   1024
#define DFF_ 512
#define TM   64           // t-rows per block
#define NCHUNK 8          // 8 chunks * K=128 = 1024
#define NSTEP 32

typedef __attribute__((ext_vector_type(8))) short bf16x8;
typedef __attribute__((ext_vector_type(4))) float f32x4;

__device__ __forceinline__ unsigned short f2bf(float x) {
  unsigned u = __float_as_uint(x);
  u += 0x7fffu + ((u >> 16) & 1u);   // RNE
  return (unsigned short)(u >> 16);
}

// async HBM -> LDS, 16 B/lane, wave-uniform LDS base + lane*16
__device__ __forceinline__ void gll16(const float* g, void* l) {
  __builtin_amdgcn_global_load_lds(
      (const __attribute__((address_space(1))) unsigned int*)g,
      (__attribute__((address_space(3))) unsigned int*)l, 16, 0, 0);
}

__device__ __forceinline__ void blk_barrier() {
  asm volatile("" ::: "memory");
  __builtin_amdgcn_s_barrier();
  asm volatile("" ::: "memory");
}

// Producer: DMA one K=128 chunk half (rows p*32..p*32+31) into F32c slot.
// Linear LDS image: byte = arow*512 + k*4 (64 rows x 128 floats).
__device__ __forceinline__ void issue_chunk(int p, int lane, const float* hbase,
                                            int c, char* slotbase) {
  char* lb = slotbase + p * 16384;
  const float* gb = hbase + (size_t)(p * 32 + (lane >> 5)) * H2 + c * 128 + (lane & 31) * 4;
  #pragma unroll
  for (int u = 0; u < 16; ++u)
    gll16(gb + (size_t)(2 * u) * H2, lb + u * 1024);
}

// Producer: convert fp32 slot -> bf16 fragment-order buffer (RNE, identical
// element mapping to the verified round-0/1 kernel).
__device__ __forceinline__ void convert_chunk(int p, int lane, const float* slot,
                                              unsigned short* dst) {
  const int v = p * 64 + lane;        // 0..127
  const int arow = v >> 1;            // 0..63 (2 lanes per row)
  const int half = v & 1;             // quads [0,16) vs [16,32)
  #pragma unroll
  for (int m = 0; m < 16; ++m) {
    int qq = half * 16 + ((m + arow) & 15);   // rotate for bank spread
    float4 x = *(const float4*)&slot[arow * 128 + qq * 4];
    ushort4 ab;
    ab.x = f2bf(x.x); ab.y = f2bf(x.y); ab.z = f2bf(x.z); ab.w = f2bf(x.w);
    int woff = (qq >> 3) * 2048 + (arow >> 4) * 512 + ((qq & 7) >> 1) * 128
             + (arow & 15) * 8 + (qq & 1) * 4;
    *(ushort4*)&dst[woff] = ab;
  }
}

// Pack U [512][1024] fp32 -> Upk in MFMA-fragment order:
// Upk[((ks*32 + ct)*64 + l)*8 + j] = bf16(U[ct*16 + (l&15)][ks*32 + (l>>4)*8 + j])
__global__ void prep_u_kernel(const float* __restrict__ U,
                              unsigned short* __restrict__ Upk) {
  int g = blockIdx.x * 256 + threadIdx.x;     // [0, 524288)
  int j  = g & 7;
  int l  = (g >> 3) & 63;
  int ct = (g >> 9) & 31;
  int ks = g >> 14;
  int f  = ct * 16 + (l & 15);
  int k  = ks * 32 + (l >> 4) * 8 + j;
  Upk[g] = f2bf(U[f * H2 + k]);
}

// ws[b][f] = s[b]·W[f] + Wb[f] + Ub[f]   (fp32, exact)
__global__ void prep_ws_kernel(const float* __restrict__ s, const float* __restrict__ W,
                               const float* __restrict__ Wb, const float* __restrict__ Ub,
                               float* __restrict__ wsm) {
  int idx = blockIdx.x * 256 + threadIdx.x;   // [0, 32*512)
  int b = idx >> 9, f = idx & 511;
  const float4* s4 = (const float4*)(s + b * 512);
  const float4* w4 = (const float4*)(W + f * 512);
  float acc = 0.f;
  #pragma unroll 4
  for (int i = 0; i < 128; ++i) {
    float4 a = s4[i], w = w4[i];
    acc += a.x * w.x + a.y * w.y + a.z * w.z + a.w * w.w;
  }
  wsm[idx] = acc + Wb[f] + Ub[f];
}

// Fused uh GEMM + tanh + energy + context.
// Producer/consumer wave specialization (separate vmcnt streams):
//   waves 0-7 (consumers): B-frag loads (Upk, L2) + LDS A reads + MFMA.
//     Their vmem queue NEVER contains gll -> compiler B-waits don't drain DMA.
//   waves 8-9 (producers): gll fp32 chunks (3-deep ring) with counted vmcnt,
//     fp32->bf16 convert into As16 double buffer.
// One raw s_barrier per chunk (no compiler vmcnt(0) drain at barriers).
__global__ __launch_bounds__(640, 3) void attn_main(
    const float* __restrict__ h, const unsigned short* __restrict__ Upk,
    const float* __restrict__ wsm, const float* __restrict__ Vw,
    const float* __restrict__ Vb, float* __restrict__ out) {
  __shared__ float F32c[3][8192];              // 3 x 32 KB fp32 chunk ring
  __shared__ unsigned short As16[2][8192];     // 2 x 16 KB bf16 fragment buffers
  __shared__ float ws_s[DFF_];
  __shared__ float V_s[DFF_];
  __shared__ float energy_part[8][TM];
  __shared__ float energy_s[TM];

  const int tid  = threadIdx.x;
  const int blk  = blockIdx.x;            // 2048 blocks
  const int b    = blk >> 6;
  const int t0   = (blk & 63) * TM;
  const int lane = tid & 63;
  const int wave = tid >> 6;              // 0..7 consumers, 8..9 producers
  const int ln15 = lane & 15;
  const int q4   = lane >> 4;

  const float* hbase = h + ((size_t)(b * T_SZ + t0)) * H2;
  const bf16x8* Upk8 = (const bf16x8*)Upk;  // fragment index = (g*32+ct)*64 + lane

  f32x4 acc[16];
  #pragma unroll
  for (int i = 0; i < 16; ++i) acc[i] = (f32x4){0.f, 0.f, 0.f, 0.f};
  bf16x8 bcur[4], bnxt[4];

  if (wave < 8) {
    // consumer prologue: epilogue tables + first B fragments
    ws_s[tid] = wsm[b * DFF_ + tid];
    V_s[tid]  = Vw[tid];
    int ub = (wave * 4) * 64 + lane;
    #pragma unroll
    for (int i = 0; i < 4; ++i) bcur[i] = Upk8[ub + i * 64];
  } else {
    // producer prologue: chunks 0..2 in flight, convert chunk 0
    const int p = wave - 8;
    issue_chunk(p, lane, hbase, 0, (char*)F32c[0]);
    issue_chunk(p, lane, hbase, 1, (char*)F32c[1]);
    issue_chunk(p, lane, hbase, 2, (char*)F32c[2]);
    asm volatile("s_waitcnt vmcnt(32)" ::: "memory");   // chunk 0 landed
    convert_chunk(p, lane, F32c[0], As16[0]);
    asm volatile("s_waitcnt lgkmcnt(0)" ::: "memory");  // writes visible
  }
  blk_barrier();

  // ---- main pipeline: 8 chunks of 4 K-steps, 1 barrier per chunk ----
  for (int c = 0; c < NCHUNK; ++c) {
    if (wave < 8) {
      const unsigned short* Ab = As16[c & 1];
      #pragma unroll
      for (int sl = 0; sl < 4; ++sl) {
        int g = c * 4 + sl;
        if (g < NSTEP - 1) {                 // depth-1 B prefetch (L2-hot)
          int ub = ((g + 1) * 32 + wave * 4) * 64 + lane;
          #pragma unroll
          for (int i = 0; i < 4; ++i) bnxt[i] = Upk8[ub + i * 64];
        }
        bf16x8 af[4];
        #pragma unroll
        for (int rt = 0; rt < 4; ++rt)
          af[rt] = *(const bf16x8*)&Ab[sl * 2048 + rt * 512 + lane * 8];
        #pragma unroll
        for (int ct2 = 0; ct2 < 4; ++ct2)
          #pragma unroll
          for (int rt = 0; rt < 4; ++rt)
            acc[ct2 * 4 + rt] =
              __builtin_amdgcn_mfma_f32_16x16x32_bf16(af[rt], bcur[ct2], acc[ct2 * 4 + rt], 0, 0, 0);
        #pragma unroll
        for (int i = 0; i < 4; ++i) bcur[i] = bnxt[i];
      }
    } else {
      const int p = wave - 8;
      if (c < NCHUNK - 1) {
        // wait chunk c+1 only; chunk c+2 (16 gll/wave) stays in flight
        if (c < NCHUNK - 2) asm volatile("s_waitcnt vmcnt(16)" ::: "memory");
        else                asm volatile("s_waitcnt vmcnt(0)"  ::: "memory");
        convert_chunk(p, lane, F32c[(c + 1) % 3], As16[(c + 1) & 1]);
        if (c < NCHUNK - 3)
          issue_chunk(p, lane, hbase, c + 3, (char*)F32c[(c + 3) % 3]);
        asm volatile("s_waitcnt lgkmcnt(0)" ::: "memory");
      }
    }
    blk_barrier();
  }

  // --- epilogue: x = tanh(ws + uh); energy partial = x·V ---
  // C/D layout: col f = tilebase + ln15, row = rt*16 + q4*4 + rg
  if (wave < 8) {
    float esum[16];
    #pragma unroll
    for (int i = 0; i < 16; ++i) esum[i] = 0.f;
    #pragma unroll
    for (int ct2 = 0; ct2 < 4; ++ct2) {
      int f = wave * 64 + ct2 * 16 + ln15;
      float wsf = ws_s[f], vf = V_s[f];
      #pragma unroll
      for (int rt = 0; rt < 4; ++rt) {
        #pragma unroll
        for (int rg = 0; rg < 4; ++rg) {
          float z = wsf + acc[ct2 * 4 + rt][rg];
          float e = __expf(2.f * z);
          float x = 1.f - 2.f / (e + 1.f);
          esum[rt * 4 + rg] += x * vf;
        }
      }
    }
    #pragma unroll
    for (int i = 0; i < 16; ++i) {
      #pragma unroll
      for (int m = 1; m < 16; m <<= 1) esum[i] += __shfl_xor(esum[i], m, 64);
    }
    if (ln15 == 0) {
      #pragma unroll
      for (int rt = 0; rt < 4; ++rt)
        #pragma unroll
        for (int rg = 0; rg < 4; ++rg)
          energy_part[wave][rt * 16 + q4 * 4 + rg] = esum[rt * 4 + rg];
    }
  }
  __syncthreads();
  if (tid < TM) {
    float e = Vb[0];
    #pragma unroll
    for (int w = 0; w < 8; ++w) e += energy_part[w][tid];
    energy_s[tid] = e;
  }
  __syncthreads();

  // --- context: out[b][e] += sum_row energy[row] * h[row][e] (L2-hot) ---
  if (tid < 512) {
    int e0 = tid * 2;
    float c0 = 0.f, c1 = 0.f;
    const float2* h2p = (const float2*)hbase + (e0 >> 1);
    #pragma unroll 8
    for (int row = 0; row < TM; ++row) {
      float en = energy_s[row];
      float2 hv = h2p[(size_t)row * (H2 / 2)];
      c0 += en * hv.x;
      c1 += en * hv.y;
    }
    atomicAdd(&out[b * H2 + e0], c0);
    atomicAdd(&out[b * H2 + e0 + 1], c1);
  }
}

extern "C" void kernel_launch(void* const* d_in, const int* in_sizes, int n_in,
                              void* d_out, int out_size, void* d_ws, size_t ws_size,
                              hipStream_t stream) {
  const float* s  = (const float*)d_in[0];
  const float* h  = (const float*)d_in[1];
  const float* Ww = (const float*)d_in[2];
  const float* Wb = (const float*)d_in[3];
  const float* Uw = (const float*)d_in[4];
  const float* Ub = (const float*)d_in[5];
  const float* Vw = (const float*)d_in[6];
  const float* Vb = (const float*)d_in[7];
  float* out = (float*)d_out;

  unsigned short* Upk = (unsigned short*)d_ws;                    // 1 MB
  float* wsm = (float*)((char*)d_ws + (size_t)NSTEP * 32768);     // 64 KB

  hipMemsetAsync(out, 0, (size_t)out_size * sizeof(float), stream);
  prep_u_kernel<<<(DFF_ * H2) / 256, 256, 0, stream>>>(Uw, Upk);
  prep_ws_kernel<<<(B_SZ * DFF_) / 256, 256, 0, stream>>>(s, Ww, Wb, Ub, wsm);
  attn_main<<<B_SZ * (T_SZ / TM), 640, 0, stream>>>(h, Upk, wsm, Vw, Vb, out);
}

// Round 3
// 866.505 us; speedup vs baseline: 1.1329x; 1.1329x over previous
//
#include <hip/hip_runtime.h>
#include <cstdint>
#include <cstddef>

// Problem constants: B=32, T=4096, 2H=1024, DFF=512
#define B_SZ 32
#define T_SZ 4096
#define H2   1024
#define DFF_ 512
#define TM   64           // t-rows per block
#define NCHUNK 16         // 16 chunks * K=64 = 1024; 2 MFMA steps/chunk
#define NSTEP 32

typedef __attribute__((ext_vector_type(8))) short bf16x8;
typedef __attribute__((ext_vector_type(4))) float f32x4;
typedef __attribute__((ext_vector_type(8))) unsigned short u16x8;

__device__ __forceinline__ unsigned short f2bf(float x) {
  unsigned u = __float_as_uint(x);
  u += 0x7fffu + ((u >> 16) & 1u);   // RNE
  return (unsigned short)(u >> 16);
}

// async HBM -> LDS, 16 B/lane, wave-uniform LDS base (HW adds lane*16)
__device__ __forceinline__ void gll16(const float* g, void* l) {
  __builtin_amdgcn_global_load_lds(
      (const __attribute__((address_space(1))) unsigned int*)g,
      (__attribute__((address_space(3))) unsigned int*)l, 16, 0, 0);
}

// compiler-level memory order pin (no instruction emitted)
__device__ __forceinline__ void memfence_sched() { asm volatile("" ::: "memory"); }

__device__ __forceinline__ void blk_barrier() {
  asm volatile("" ::: "memory");
  __builtin_amdgcn_s_barrier();
  asm volatile("" ::: "memory");
}

// Pack U [512][1024] fp32 -> Upk in MFMA-fragment order:
// Upk[((ks*32 + ct)*64 + l)*8 + j] = bf16(U[ct*16 + (l&15)][ks*32 + (l>>4)*8 + j])
__global__ void prep_u_kernel(const float* __restrict__ U,
                              unsigned short* __restrict__ Upk) {
  int g = blockIdx.x * 256 + threadIdx.x;     // [0, 524288)
  int j  = g & 7;
  int l  = (g >> 3) & 63;
  int ct = (g >> 9) & 31;
  int ks = g >> 14;
  int f  = ct * 16 + (l & 15);
  int k  = ks * 32 + (l >> 4) * 8 + j;
  Upk[g] = f2bf(U[f * H2 + k]);
}

// ws[b][f] = s[b]·W[f] + Wb[f] + Ub[f]   (fp32, exact)
__global__ void prep_ws_kernel(const float* __restrict__ s, const float* __restrict__ W,
                               const float* __restrict__ Wb, const float* __restrict__ Ub,
                               float* __restrict__ wsm) {
  int idx = blockIdx.x * 256 + threadIdx.x;   // [0, 32*512)
  int b = idx >> 9, f = idx & 511;
  const float4* s4 = (const float4*)(s + b * 512);
  const float4* w4 = (const float4*)(W + f * 512);
  float acc = 0.f;
  #pragma unroll 4
  for (int i = 0; i < 128; ++i) {
    float4 a = s4[i], w = w4[i];
    acc += a.x * w.x + a.y * w.y + a.z * w.z + a.w * w.w;
  }
  wsm[idx] = acc + Wb[f] + Ub[f];
}

// Fused uh GEMM + tanh + energy + context.
// Ordering invariant (vmcnt retires IN ORDER): everything consumed during
// chunk c (B fragments, As16) is ISSUED BEFORE gll(c+1). So compiler waits
// for B are vmcnt(2) — the pending chunk DMA stays in flight across the
// whole compute phase. One raw s_barrier per chunk; each wave converts the
// rows its own gll staged (own-wave vmcnt(0) suffices before convert).
__global__ __launch_bounds__(512, 4) void attn_main(
    const float* __restrict__ h, const unsigned short* __restrict__ Upk,
    const float* __restrict__ wsm, const float* __restrict__ Vw,
    const float* __restrict__ Vb, float* __restrict__ out) {
  __shared__ float F32c[2][4096];              // 2 x 16 KB fp32 chunk dbuf
  __shared__ unsigned short As16[2][4096];     // 2 x 8 KB bf16 fragment dbuf
  __shared__ float ws_s[DFF_];
  __shared__ float V_s[DFF_];
  __shared__ float energy_part[8][TM];
  __shared__ float energy_s[TM];

  const int tid  = threadIdx.x;
  const int blk  = blockIdx.x;            // 2048 blocks
  const int b    = blk >> 6;
  const int t0   = (blk & 63) * TM;
  const int lane = tid & 63;
  const int wave = tid >> 6;              // col-group 0..7
  const int ln15 = lane & 15;
  const int q4   = lane >> 4;

  ws_s[tid] = wsm[b * DFF_ + tid];
  V_s[tid]  = Vw[tid];

  const float* hbase = h + ((size_t)(b * T_SZ + t0)) * H2;

  // gll staging: wave w stages its own rows [8w, 8w+8): 2 insts of 1 KB.
  // inst u covers rows 8w+4u+(l>>4), bytes (l&15)*16 of the 256 B row.
  const float* gsrc = hbase + (size_t)(8 * wave + (lane >> 4)) * H2 + (lane & 15) * 4;

  // convert mapping (own rows): lane -> (row, 8-float k-group)
  const int crow = 8 * wave + (lane >> 3);
  const int ckg  = lane & 7;
  const int cread  = crow * 64 + ckg * 8;                       // float idx in F32c
  const int cwrite = (ckg >> 2) * 2048 + (crow >> 4) * 512
                   + ((ckg & 3) * 16 + (crow & 15)) * 8;        // short idx in As16

  const bf16x8* Upk8 = (const bf16x8*)Upk;  // fragment index = (g*32+cg*4+i)*64 + lane

  f32x4 acc[16];
  #pragma unroll
  for (int i = 0; i < 16; ++i) acc[i] = (f32x4){0.f, 0.f, 0.f, 0.f};
  bf16x8 bcur[8];

  // ---- prologue: gll(0); B(0); gll(1); wait gll(0); convert(0) ----
  gll16(gsrc,            (char*)&F32c[0][0] + wave * 2048);
  gll16(gsrc + 4 * H2,   (char*)&F32c[0][0] + wave * 2048 + 1024);
  memfence_sched();
  #pragma unroll
  for (int st = 0; st < 2; ++st)
    #pragma unroll
    for (int i = 0; i < 4; ++i)
      bcur[st * 4 + i] = Upk8[(size_t)(st * 32 + wave * 4 + i) * 64 + lane];
  memfence_sched();
  gll16(gsrc + 64,          (char*)&F32c[1][0] + wave * 2048);
  gll16(gsrc + 64 + 4 * H2, (char*)&F32c[1][0] + wave * 2048 + 1024);
  asm volatile("s_waitcnt vmcnt(10)" ::: "memory");   // gll(0) landed (B(0)+gll(1)=10 younger)
  {
    const float* src = &F32c[0][cread];
    float4 x0 = *(const float4*)src;
    float4 x1 = *(const float4*)(src + 4);
    u16x8 o;
    o[0] = f2bf(x0.x); o[1] = f2bf(x0.y); o[2] = f2bf(x0.z); o[3] = f2bf(x0.w);
    o[4] = f2bf(x1.x); o[5] = f2bf(x1.y); o[6] = f2bf(x1.z); o[7] = f2bf(x1.w);
    *(u16x8*)&As16[0][cwrite] = o;
  }
  blk_barrier();

  // ---- main pipeline: 16 chunks, 1 barrier each ----
  for (int c = 0; c < NCHUNK; ++c) {
    // compute chunk c: 2 steps x {4 ds_read_b128 + 16 MFMA}
    const unsigned short* Ab = &As16[c & 1][0];
    #pragma unroll
    for (int st = 0; st < 2; ++st) {
      #pragma unroll
      for (int rt = 0; rt < 4; ++rt) {
        bf16x8 af = *(const bf16x8*)&Ab[st * 2048 + rt * 512 + lane * 8];
        #pragma unroll
        for (int ct2 = 0; ct2 < 4; ++ct2)
          acc[ct2 * 4 + rt] =
            __builtin_amdgcn_mfma_f32_16x16x32_bf16(af, bcur[st * 4 + ct2],
                                                    acc[ct2 * 4 + rt], 0, 0, 0);
      }
    }
    if (c < NCHUNK - 1) {
      // gll(c+1) is the only outstanding vmem here
      asm volatile("s_waitcnt vmcnt(0)" ::: "memory");
      {  // convert chunk c+1 (rows this wave staged) -> As16[(c+1)&1]
        const float* src = &F32c[(c + 1) & 1][cread];
        float4 x0 = *(const float4*)src;
        float4 x1 = *(const float4*)(src + 4);
        u16x8 o;
        o[0] = f2bf(x0.x); o[1] = f2bf(x0.y); o[2] = f2bf(x0.z); o[3] = f2bf(x0.w);
        o[4] = f2bf(x1.x); o[5] = f2bf(x1.y); o[6] = f2bf(x1.z); o[7] = f2bf(x1.w);
        *(u16x8*)&As16[(c + 1) & 1][cwrite] = o;
      }
      blk_barrier();
      // B(c+1) BEFORE gll(c+2): keeps B older than the pending DMA
      const int g0 = (c + 1) * 2;
      #pragma unroll
      for (int st = 0; st < 2; ++st)
        #pragma unroll
        for (int i = 0; i < 4; ++i)
          bcur[st * 4 + i] = Upk8[(size_t)((g0 + st) * 32 + wave * 4 + i) * 64 + lane];
      memfence_sched();
      if (c < NCHUNK - 2) {
        const float* gs = gsrc + (c + 2) * 64;
        char* ld = (char*)&F32c[c & 1][0] + wave * 2048;
        gll16(gs,          ld);
        gll16(gs + 4 * H2, ld + 1024);
      }
    }
  }

  // --- epilogue: x = tanh(ws + uh); energy partial = x·V ---
  // C/D layout: col f = cg*64 + ct2*16 + ln15, row = rt*16 + q4*4 + rg
  float esum[16];
  #pragma unroll
  for (int i = 0; i < 16; ++i) esum[i] = 0.f;
  #pragma unroll
  for (int ct2 = 0; ct2 < 4; ++ct2) {
    int f = wave * 64 + ct2 * 16 + ln15;
    float wsf = ws_s[f], vf = V_s[f];
    #pragma unroll
    for (int rt = 0; rt < 4; ++rt) {
      #pragma unroll
      for (int rg = 0; rg < 4; ++rg) {
        float z = wsf + acc[ct2 * 4 + rt][rg];
        float e = __expf(2.f * z);
        float x = 1.f - 2.f / (e + 1.f);
        esum[rt * 4 + rg] += x * vf;
      }
    }
  }
  #pragma unroll
  for (int i = 0; i < 16; ++i) {
    #pragma unroll
    for (int m = 1; m < 16; m <<= 1) esum[i] += __shfl_xor(esum[i], m, 64);
  }
  if (ln15 == 0) {
    #pragma unroll
    for (int rt = 0; rt < 4; ++rt)
      #pragma unroll
      for (int rg = 0; rg < 4; ++rg)
        energy_part[wave][rt * 16 + q4 * 4 + rg] = esum[rt * 4 + rg];
  }
  __syncthreads();
  if (tid < TM) {
    float e = Vb[0];
    #pragma unroll
    for (int w = 0; w < 8; ++w) e += energy_part[w][tid];
    energy_s[tid] = e;
  }
  __syncthreads();

  // --- context: out[b][e] += sum_row energy[row] * h[row][e] (L2-hot) ---
  int e0 = tid * 2;
  float c0 = 0.f, c1 = 0.f;
  const float2* h2p = (const float2*)hbase + (e0 >> 1);
  #pragma unroll 8
  for (int row = 0; row < TM; ++row) {
    float en = energy_s[row];
    float2 hv = h2p[(size_t)row * (H2 / 2)];
    c0 += en * hv.x;
    c1 += en * hv.y;
  }
  atomicAdd(&out[b * H2 + e0], c0);
  atomicAdd(&out[b * H2 + e0 + 1], c1);
}

extern "C" void kernel_launch(void* const* d_in, const int* in_sizes, int n_in,
                              void* d_out, int out_size, void* d_ws, size_t ws_size,
                              hipStream_t stream) {
  const float* s  = (const float*)d_in[0];
  const float* h  = (const float*)d_in[1];
  const float* Ww = (const float*)d_in[2];
  const float* Wb = (const float*)d_in[3];
  const float* Uw = (const float*)d_in[4];
  const float* Ub = (const float*)d_in[5];
  const float* Vw = (const float*)d_in[6];
  const float* Vb = (const float*)d_in[7];
  float* out = (float*)d_out;

  unsigned short* Upk = (unsigned short*)d_ws;                    // 1 MB
  float* wsm = (float*)((char*)d_ws + (size_t)NSTEP * 32768);     // 64 KB

  hipMemsetAsync(out, 0, (size_t)out_size * sizeof(float), stream);
  prep_u_kernel<<<(DFF_ * H2) / 256, 256, 0, stream>>>(Uw, Upk);
  prep_ws_kernel<<<(B_SZ * DFF_) / 256, 256, 0, stream>>>(s, Ww, Wb, Ub, wsm);
  attn_main<<<B_SZ * (T_SZ / TM), 512, 0, stream>>>(h, Upk, wsm, Vw, Vb, out);
}

// Round 4
// 824.291 us; speedup vs baseline: 1.1909x; 1.0512x over previous
//
#include <hip/hip_runtime.h>
#include <cstdint>
#include <cstddef>

// Problem constants: B=32, T=4096, 2H=1024, DFF=512
#define B_SZ 32
#define T_SZ 4096
#define H2   1024
#define DFF_ 512
#define TM   64           // t-rows per block
#define NCHUNK 16         // 16 chunks * K=64 = 1024; 2 MFMA steps/chunk
#define NSTEP 32

typedef __attribute__((ext_vector_type(8))) short bf16x8;
typedef __attribute__((ext_vector_type(4))) float f32x4;
typedef __attribute__((ext_vector_type(8))) unsigned short u16x8;

__device__ __forceinline__ unsigned short f2bf(float x) {
  unsigned u = __float_as_uint(x);
  u += 0x7fffu + ((u >> 16) & 1u);   // RNE
  return (unsigned short)(u >> 16);
}

// async HBM -> LDS, 16 B/lane, wave-uniform LDS base (HW adds lane*16)
__device__ __forceinline__ void gll16(const float* g, void* l) {
  __builtin_amdgcn_global_load_lds(
      (const __attribute__((address_space(1))) unsigned int*)g,
      (__attribute__((address_space(3))) unsigned int*)l, 16, 0, 0);
}

// compiler-level memory order pin (no instruction emitted)
__device__ __forceinline__ void memfence_sched() { asm volatile("" ::: "memory"); }

// Pack U [512][1024] fp32 -> Upk in MFMA-fragment order:
// Upk[((ks*32 + ct)*64 + l)*8 + j] = bf16(U[ct*16 + (l&15)][ks*32 + (l>>4)*8 + j])
__global__ void prep_u_kernel(const float* __restrict__ U,
                              unsigned short* __restrict__ Upk) {
  int g = blockIdx.x * 256 + threadIdx.x;     // [0, 524288)
  int j  = g & 7;
  int l  = (g >> 3) & 63;
  int ct = (g >> 9) & 31;
  int ks = g >> 14;
  int f  = ct * 16 + (l & 15);
  int k  = ks * 32 + (l >> 4) * 8 + j;
  Upk[g] = f2bf(U[f * H2 + k]);
}

// ws[b][f] = s[b]·W[f] + Wb[f] + Ub[f]   (fp32, exact)
__global__ void prep_ws_kernel(const float* __restrict__ s, const float* __restrict__ W,
                               const float* __restrict__ Wb, const float* __restrict__ Ub,
                               float* __restrict__ wsm) {
  int idx = blockIdx.x * 256 + threadIdx.x;   // [0, 32*512)
  int b = idx >> 9, f = idx & 511;
  const float4* s4 = (const float4*)(s + b * 512);
  const float4* w4 = (const float4*)(W + f * 512);
  float acc = 0.f;
  #pragma unroll 4
  for (int i = 0; i < 128; ++i) {
    float4 a = s4[i], w = w4[i];
    acc += a.x * w.x + a.y * w.y + a.z * w.z + a.w * w.w;
  }
  wsm[idx] = acc + Wb[f] + Ub[f];
}

// Fused uh GEMM + tanh + energy + context.
// Stream-overlap schedule: all ISSUE work (convert, gll, B) is placed so the
// compute phase covers the latencies:
//   iter c: wait own gll(c+1) [counted vmcnt -> gll(c+2)+B(c) stay in flight]
//           -> convert(c+1) -> issue gll(c+3) -> COMPUTE c
//           -> load B(c+1) -> lgkmcnt(0) -> s_barrier.
// F32c is a 3-slot ring of wave-private 2KB slices (no cross-wave hazard);
// 2 gll chunks are in flight per wave across the whole compute phase.
__global__ __launch_bounds__(512, 4) void attn_main(
    const float* __restrict__ h, const unsigned short* __restrict__ Upk,
    const float* __restrict__ wsm, const float* __restrict__ Vw,
    const float* __restrict__ Vb, float* __restrict__ out) {
  __shared__ float F32c[3][4096];              // 3 x 16 KB fp32 chunk ring
  __shared__ unsigned short As16[2][4096];     // 2 x 8 KB bf16 fragment dbuf
  __shared__ float ws_s[DFF_];
  __shared__ float V_s[DFF_];
  __shared__ float energy_part[8][TM];
  __shared__ float energy_s[TM];

  const int tid  = threadIdx.x;
  const int blk  = blockIdx.x;            // 2048 blocks
  const int b    = blk >> 6;
  const int t0   = (blk & 63) * TM;
  const int lane = tid & 63;
  const int wave = tid >> 6;              // col-group 0..7
  const int ln15 = lane & 15;
  const int q4   = lane >> 4;

  ws_s[tid] = wsm[b * DFF_ + tid];
  V_s[tid]  = Vw[tid];

  const float* hbase = h + ((size_t)(b * T_SZ + t0)) * H2;

  // gll staging: wave w stages its own rows [8w, 8w+8): 2 insts of 1 KB.
  const float* gsrc = hbase + (size_t)(8 * wave + (lane >> 4)) * H2 + (lane & 15) * 4;

  // convert mapping (own rows): lane -> (row, 8-float k-group)
  const int crow = 8 * wave + (lane >> 3);
  const int ckg  = lane & 7;
  const int cread = crow * 64 + ckg * 8;                        // float idx in F32c slot
  int cwq = (ckg & 3) * 16 + (crow & 15);                       // q-slot, 0..63
  cwq ^= (cwq >> 4) & 3;                                        // bank swizzle (write)
  const int cwrite = (ckg >> 2) * 2048 + (crow >> 4) * 512 + cwq * 8;
  const int lrd = (lane ^ ((lane >> 4) & 3)) * 8;               // swizzled read slot

  const bf16x8* Upk8 = (const bf16x8*)Upk;  // fragment index = (g*32+cg*4+i)*64 + lane

  f32x4 acc[16];
  #pragma unroll
  for (int i = 0; i < 16; ++i) acc[i] = (f32x4){0.f, 0.f, 0.f, 0.f};
  bf16x8 bcur[8];

  // ---- prologue: gll(0,1,2); B(0); wait gll(0); convert(0); barrier ----
  {
    char* lb = (char*)&F32c[0][0] + wave * 2048;
    gll16(gsrc,          lb);
    gll16(gsrc + 4 * H2, lb + 1024);
    lb = (char*)&F32c[1][0] + wave * 2048;
    gll16(gsrc + 64,          lb);
    gll16(gsrc + 64 + 4 * H2, lb + 1024);
    lb = (char*)&F32c[2][0] + wave * 2048;
    gll16(gsrc + 128,          lb);
    gll16(gsrc + 128 + 4 * H2, lb + 1024);
  }
  memfence_sched();                    // pin B(0) loads AFTER the glls
  #pragma unroll
  for (int st = 0; st < 2; ++st)
    #pragma unroll
    for (int i = 0; i < 4; ++i)
      bcur[st * 4 + i] = Upk8[(size_t)(st * 32 + wave * 4 + i) * 64 + lane];
  memfence_sched();
  asm volatile("s_waitcnt vmcnt(12)" ::: "memory");   // gll(0) landed
  {
    const float* src = &F32c[0][cread];
    float4 x0 = *(const float4*)src;
    float4 x1 = *(const float4*)(src + 4);
    u16x8 o;
    o[0] = f2bf(x0.x); o[1] = f2bf(x0.y); o[2] = f2bf(x0.z); o[3] = f2bf(x0.w);
    o[4] = f2bf(x1.x); o[5] = f2bf(x1.y); o[6] = f2bf(x1.z); o[7] = f2bf(x1.w);
    *(u16x8*)&As16[0][cwrite] = o;
  }
  asm volatile("s_waitcnt lgkmcnt(0)" ::: "memory");
  __builtin_amdgcn_s_barrier();
  memfence_sched();

  // ---- main pipeline: 16 chunks, 1 barrier each ----
  int s0 = 0;                          // = c % 3 (ring index)
  for (int c = 0; c < NCHUNK; ++c) {
    int s1 = s0 + 1; if (s1 == 3) s1 = 0;
    if (c < NCHUNK - 1) {
      // drain own gll(c+1); keep gll(c+2) [if any] + B(c) in flight
      if (c < NCHUNK - 2) { asm volatile("s_waitcnt vmcnt(10)" ::: "memory"); }
      else                { asm volatile("s_waitcnt vmcnt(8)"  ::: "memory"); }
      {  // convert chunk c+1 (rows this wave staged) -> As16[(c+1)&1]
        const float* src = &F32c[s1][cread];
        float4 x0 = *(const float4*)src;
        float4 x1 = *(const float4*)(src + 4);
        u16x8 o;
        o[0] = f2bf(x0.x); o[1] = f2bf(x0.y); o[2] = f2bf(x0.z); o[3] = f2bf(x0.w);
        o[4] = f2bf(x1.x); o[5] = f2bf(x1.y); o[6] = f2bf(x1.z); o[7] = f2bf(x1.w);
        *(u16x8*)&As16[(c + 1) & 1][cwrite] = o;
      }
      if (c <= NCHUNK - 4) {           // issue gll(c+3) into slot c%3 (free)
        const float* gs = gsrc + (size_t)(c + 3) * 64;
        char* lb = (char*)&F32c[s0][0] + wave * 2048;
        gll16(gs,          lb);
        gll16(gs + 4 * H2, lb + 1024);
      }
      memfence_sched();
    }
    // compute chunk c: 2 steps x {4 ds_read_b128 + 16 MFMA}
    const unsigned short* Ab = &As16[c & 1][0];
    #pragma unroll
    for (int st = 0; st < 2; ++st) {
      #pragma unroll
      for (int rt = 0; rt < 4; ++rt) {
        bf16x8 af = *(const bf16x8*)&Ab[st * 2048 + rt * 512 + lrd];
        #pragma unroll
        for (int ct2 = 0; ct2 < 4; ++ct2)
          acc[ct2 * 4 + rt] =
            __builtin_amdgcn_mfma_f32_16x16x32_bf16(af, bcur[st * 4 + ct2],
                                                    acc[ct2 * 4 + rt], 0, 0, 0);
      }
    }
    if (c < NCHUNK - 1) {
      // load B(c+1) (L2-hot; latency hidden by boundary work + next compute)
      const int g0 = (c + 1) * 2;
      #pragma unroll
      for (int st = 0; st < 2; ++st)
        #pragma unroll
        for (int i = 0; i < 4; ++i)
          bcur[st * 4 + i] = Upk8[(size_t)((g0 + st) * 32 + wave * 4 + i) * 64 + lane];
      asm volatile("s_waitcnt lgkmcnt(0)" ::: "memory");  // ds_write visible, reads done
      __builtin_amdgcn_s_barrier();
      memfence_sched();
    }
    s0 = s1;
  }

  // --- epilogue: x = tanh(ws + uh); energy partial = x·V ---
  // C/D layout: col f = cg*64 + ct2*16 + ln15, row = rt*16 + q4*4 + rg
  float esum[16];
  #pragma unroll
  for (int i = 0; i < 16; ++i) esum[i] = 0.f;
  #pragma unroll
  for (int ct2 = 0; ct2 < 4; ++ct2) {
    int f = wave * 64 + ct2 * 16 + ln15;
    float wsf = ws_s[f], vf = V_s[f];
    #pragma unroll
    for (int rt = 0; rt < 4; ++rt) {
      #pragma unroll
      for (int rg = 0; rg < 4; ++rg) {
        float z = wsf + acc[ct2 * 4 + rt][rg];
        float e = __expf(2.f * z);
        float x = 1.f - 2.f / (e + 1.f);
        esum[rt * 4 + rg] += x * vf;
      }
    }
  }
  #pragma unroll
  for (int i = 0; i < 16; ++i) {
    #pragma unroll
    for (int m = 1; m < 16; m <<= 1) esum[i] += __shfl_xor(esum[i], m, 64);
  }
  if (ln15 == 0) {
    #pragma unroll
    for (int rt = 0; rt < 4; ++rt)
      #pragma unroll
      for (int rg = 0; rg < 4; ++rg)
        energy_part[wave][rt * 16 + q4 * 4 + rg] = esum[rt * 4 + rg];
  }
  __syncthreads();
  if (tid < TM) {
    float e = Vb[0];
    #pragma unroll
    for (int w = 0; w < 8; ++w) e += energy_part[w][tid];
    energy_s[tid] = e;
  }
  __syncthreads();

  // --- context: out[b][e] += sum_row energy[row] * h[row][e] (L2-hot) ---
  int e0 = tid * 2;
  float c0 = 0.f, c1 = 0.f;
  const float2* h2p = (const float2*)hbase + (e0 >> 1);
  #pragma unroll 8
  for (int row = 0; row < TM; ++row) {
    float en = energy_s[row];
    float2 hv = h2p[(size_t)row * (H2 / 2)];
    c0 += en * hv.x;
    c1 += en * hv.y;
  }
  atomicAdd(&out[b * H2 + e0], c0);
  atomicAdd(&out[b * H2 + e0 + 1], c1);
}

extern "C" void kernel_launch(void* const* d_in, const int* in_sizes, int n_in,
                              void* d_out, int out_size, void* d_ws, size_t ws_size,
                              hipStream_t stream) {
  const float* s  = (const float*)d_in[0];
  const float* h  = (const float*)d_in[1];
  const float* Ww = (const float*)d_in[2];
  const float* Wb = (const float*)d_in[3];
  const float* Uw = (const float*)d_in[4];
  const float* Ub = (const float*)d_in[5];
  const float* Vw = (const float*)d_in[6];
  const float* Vb = (const float*)d_in[7];
  float* out = (float*)d_out;

  unsigned short* Upk = (unsigned short*)d_ws;                    // 1 MB
  float* wsm = (float*)((char*)d_ws + (size_t)NSTEP * 32768);     // 64 KB

  hipMemsetAsync(out, 0, (size_t)out_size * sizeof(float), stream);
  prep_u_kernel<<<(DFF_ * H2) / 256, 256, 0, stream>>>(Uw, Upk);
  prep_ws_kernel<<<(B_SZ * DFF_) / 256, 256, 0, stream>>>(s, Ww, Wb, Ub, wsm);
  attn_main<<<B_SZ * (T_SZ / TM), 512, 0, stream>>>(h, Upk, wsm, Vw, Vb, out);
}